// Round 8
// baseline (382.518 us; speedup 1.0000x reference)
//
#include <hip/hip_runtime.h>
#include <math.h>

#define K_CODES 512
#define DIM 64
#define NPTS (32 * 4096)   // 131072 points (B*HW)
#define NQ (NPTS * DIM)    // 8388608 quant_out elements
#define KSPLIT 4
#define KRANGE (K_CODES / KSPLIT) // 128 codes per wave
#define PPB 128            // points per block: 2 per lane
#define CHUNK 16           // codes per staged LDS chunk
#define NCHUNK (KRANGE / CHUNK) // 8

// d_out layout (floats): [quant_out: 8388608][loss: 1][indices-as-float: 131072]

__global__ void init_kernel(float* __restrict__ loss) { loss[0] = 0.0f; }

// 256 thr = 4 waves. Wave w scans codes [w*128, w*128+128) for the block's 128
// points (2 per lane), streaming its code slice through a wave-private
// double-buffered LDS stage (global coalesced -> ds_write_b128 -> broadcast
// ds_read_b128). No barriers in the main loop.
__global__ __launch_bounds__(256, 2) void vq_kernel(const float* __restrict__ qin,
                                                    const float* __restrict__ cb,
                                                    float* __restrict__ out,
                                                    float* __restrict__ loss_acc,
                                                    float* __restrict__ idx_out) {
    __shared__ float shalf[K_CODES];
    __shared__ float4 stage[KSPLIT][2][CHUNK * 16]; // 32 KB
    __shared__ float sscore[KSPLIT][PPB];
    __shared__ int   sidx[KSPLIT][PPB];
    __shared__ int   sfinal[PPB];
    __shared__ float wsum[4];

    int tid = threadIdx.x, lane = tid & 63, w = tid >> 6;

    // cooperative 0.5*||e_k||^2 table
    for (int kk = 0; kk < K_CODES; kk += 256) {
        int k = kk + tid;
        const float4* c4 = (const float4*)(cb + k * DIM);
        float s0 = 0.f, s1 = 0.f, s2 = 0.f, s3 = 0.f;
#pragma unroll
        for (int i = 0; i < 16; ++i) {
            float4 c = c4[i];
            s0 = fmaf(c.x, c.x, s0); s1 = fmaf(c.y, c.y, s1);
            s2 = fmaf(c.z, c.z, s2); s3 = fmaf(c.w, c.w, s3);
        }
        shalf[k] = 0.5f * ((s0 + s1) + (s2 + s3));
    }

    int n0 = blockIdx.x * PPB + lane; // pt0; pt1 = n0+64 (same b)
    int b = n0 >> 12, hw = n0 & 4095;
    const float* base0 = qin + ((size_t)b << 18) + hw;
    const float* base1 = base0 + 64;

    float x0[DIM], x1[DIM];
#pragma unroll
    for (int d = 0; d < DIM; ++d) {
        x0[d] = base0[(size_t)d << 12];
        x1[d] = base1[(size_t)d << 12];
    }

    __syncthreads(); // shalf ready

    int k0 = __builtin_amdgcn_readfirstlane(w * KRANGE);
    const float4* cbase = (const float4*)cb + (size_t)k0 * 16; // wave's slice

    // stage chunk 0
    {
        float4 p0 = cbase[0 * 64 + lane], p1 = cbase[1 * 64 + lane];
        float4 p2 = cbase[2 * 64 + lane], p3 = cbase[3 * 64 + lane];
        stage[w][0][0 * 64 + lane] = p0; stage[w][0][1 * 64 + lane] = p1;
        stage[w][0][2 * 64 + lane] = p2; stage[w][0][3 * 64 + lane] = p3;
    }

    float bs0 = -INFINITY, bs1 = -INFINITY;
    int bi0 = k0, bi1 = k0;

    for (int c = 0; c < NCHUNK; ++c) {
        int cur = c & 1;
        float4 q0, q1, q2, q3;
        if (c + 1 < NCHUNK) { // prefetch next chunk into regs
            const float4* src = cbase + (c + 1) * (CHUNK * 16);
            q0 = src[0 * 64 + lane]; q1 = src[1 * 64 + lane];
            q2 = src[2 * 64 + lane]; q3 = src[3 * 64 + lane];
        }
        const float4* sb = &stage[w][cur][0];
        int kb = k0 + c * CHUNK;
#pragma unroll 4
        for (int kk = 0; kk < CHUNK; ++kk) {
            float a0 = 0.f, a1 = 0.f, a2 = 0.f, a3 = 0.f;
            float g0 = 0.f, g1 = 0.f, g2 = 0.f, g3 = 0.f;
#pragma unroll
            for (int i = 0; i < 16; ++i) {
                float4 cv = sb[kk * 16 + i]; // uniform addr -> LDS broadcast
                a0 = fmaf(x0[4 * i + 0], cv.x, a0);
                a1 = fmaf(x0[4 * i + 1], cv.y, a1);
                a2 = fmaf(x0[4 * i + 2], cv.z, a2);
                a3 = fmaf(x0[4 * i + 3], cv.w, a3);
                g0 = fmaf(x1[4 * i + 0], cv.x, g0);
                g1 = fmaf(x1[4 * i + 1], cv.y, g1);
                g2 = fmaf(x1[4 * i + 2], cv.z, g2);
                g3 = fmaf(x1[4 * i + 3], cv.w, g3);
            }
            int k = kb + kk;
            float sh = shalf[k];
            float sc0 = ((a0 + a1) + (a2 + a3)) - sh;
            float sc1 = ((g0 + g1) + (g2 + g3)) - sh;
            if (sc0 > bs0) { bs0 = sc0; bi0 = k; } // strict: smallest k wins ties
            if (sc1 > bs1) { bs1 = sc1; bi1 = k; }
        }
        if (c + 1 < NCHUNK) {
            int nxt = cur ^ 1;
            stage[w][nxt][0 * 64 + lane] = q0; stage[w][nxt][1 * 64 + lane] = q1;
            stage[w][nxt][2 * 64 + lane] = q2; stage[w][nxt][3 * 64 + lane] = q3;
        }
    }

    sscore[w][lane] = bs0;      sidx[w][lane] = bi0;
    sscore[w][lane + 64] = bs1; sidx[w][lane + 64] = bi1;
    __syncthreads();

    // combine ranges in ascending order (strict > => smallest k on ties)
    if (w == 0) {
#pragma unroll
        for (int pp = 0; pp < 2; ++pp) {
            int p = lane + pp * 64;
            float s = sscore[0][p];
            int i = sidx[0][p];
#pragma unroll
            for (int ww = 1; ww < KSPLIT; ++ww) {
                float s2 = sscore[ww][p];
                int i2 = sidx[ww][p];
                if (s2 > s) { s = s2; i = i2; }
            }
            sfinal[p] = i;
            idx_out[blockIdx.x * PPB + p] = (float)i;
        }
    }
    __syncthreads();

    // gather + store + loss: wave w handles dims [w*16, w*16+16) for both pts
    int ci0 = sfinal[lane], ci1 = sfinal[lane + 64];
    float* obase0 = out + ((size_t)b << 18) + hw;
    float* obase1 = obase0 + 64;
    float lsum;
#define GBODY(W)                                                        \
    {                                                                   \
        const float* cr0 = cb + ci0 * DIM + (W) * 16;                   \
        const float* cr1 = cb + ci1 * DIM + (W) * 16;                   \
        float l0 = 0.f, l1 = 0.f;                                       \
        _Pragma("unroll") for (int j = 0; j < 16; ++j) {                \
            float v0 = cr0[j], v1 = cr1[j];                             \
            obase0[(size_t)((W) * 16 + j) << 12] = v0;                  \
            obase1[(size_t)((W) * 16 + j) << 12] = v1;                  \
            float e0 = v0 - x0[(W) * 16 + j];                           \
            float e1 = v1 - x1[(W) * 16 + j];                           \
            l0 = fmaf(e0, e0, l0);                                      \
            l1 = fmaf(e1, e1, l1);                                      \
        }                                                               \
        lsum = l0 + l1;                                                 \
    }
    if (w == 0) GBODY(0)
    else if (w == 1) GBODY(1)
    else if (w == 2) GBODY(2)
    else GBODY(3)
#undef GBODY

    float s = lsum;
#pragma unroll
    for (int off = 32; off > 0; off >>= 1) s += __shfl_down(s, off);
    if (lane == 0) wsum[w] = s;
    __syncthreads();
    if (tid == 0) atomicAdd(loss_acc, (wsum[0] + wsum[1]) + (wsum[2] + wsum[3]));
}

__global__ void finalize_kernel(float* __restrict__ loss) {
    loss[0] = 1.2f * loss[0] / 8388608.0f; // (1+BETA)*mean
}

extern "C" void kernel_launch(void* const* d_in, const int* in_sizes, int n_in,
                              void* d_out, int out_size, void* d_ws, size_t ws_size,
                              hipStream_t stream) {
    const float* qin = (const float*)d_in[0]; // (32,64,64,64) f32
    const float* cb = (const float*)d_in[1];  // (512,64) f32
    float* out = (float*)d_out;
    float* loss_out = out + NQ;
    float* idx_out = out + NQ + 1;

    init_kernel<<<1, 1, 0, stream>>>(loss_out);
    vq_kernel<<<NPTS / PPB, 256, 0, stream>>>(qin, cb, out, loss_out, idx_out);
    finalize_kernel<<<1, 1, 0, stream>>>(loss_out);
}